// Round 16
// baseline (196.676 us; speedup 1.0000x reference)
//
#include <hip/hip_runtime.h>

typedef unsigned int uint;
typedef unsigned short ushort;
typedef __attribute__((ext_vector_type(8))) short short8;   // 8 bf16 = 4 VGPRs
typedef __attribute__((ext_vector_type(4))) float floatx4;  // MFMA C/D

#define N_NODES 50000
#define N_EDGES 1600000
#define DIM 128
#define LN_EPS 1e-10f

#define ROWS_PER_BUCKET 64
#define N_BUCKETS 782            // ceil(50000/64)
#define BUCKET_CAP 2560          // mean 2048, +11 sigma
#define EPB 3125                 // edges per scatter block (512*3125 = 1.6M exact)
#define SB 512                   // scatter blocks -> 2 per CU, 4-deep residency
#define FCB 3125                 // feat-convert blocks (512 thr, 1 float4 each)
#define GPAD 16                  // gcnt stride in ints (64 B/counter)
#define CAPR 76                  // per-row agg list slots (mean 32, +11 sigma)

__device__ __forceinline__ uint f2bf(float x) {
    uint u = __float_as_uint(x);
    return (u + 0x7FFFu + ((u >> 16) & 1u)) >> 16;   // RNE to bf16
}

// ---------------------------------------------------------------------------
// prep = scatter [0,SB) + feat convert + W pack, fused.
// R15 post-mortem: scatter was 196 single-resident 75-KB-LDS blocks -- the
// per-block critical path (~5 LDS ops/edge + barrier phases) ran with ZERO
// block-level overlap.  Now 512-thr / 34.7 KB blocks, 4 resident per CU:
// co-resident blocks' phases interleave, saturating the LDS pipe and hiding
// the global-latency phases.  Algorithm unchanged: histogram -> padded
// global reservation + LDS scan -> stage-by-bucket -> clustered flush.
// ---------------------------------------------------------------------------
__global__ __launch_bounds__(512) void prep(
    const float* __restrict__ feat, const float* __restrict__ W,
    const int* __restrict__ rows, const int* __restrict__ cols,
    const float* __restrict__ vals, int* __restrict__ gcnt,
    int2* __restrict__ perm, uint* __restrict__ featb_u,
    ushort* __restrict__ wbf)
{
    __shared__ int  cnt[N_BUCKETS];
    __shared__ int  gbase[N_BUCKETS];
    __shared__ int  lcur[N_BUCKETS];
    __shared__ int  csum[64];
    __shared__ int2 stageE[EPB];        // 25 KB
    const int bx = blockIdx.x;
    const int t  = threadIdx.x;

    if (bx >= SB) {
        int cb = bx - SB;
        if (cb < FCB) {                 // feat fp32 -> packed bf16
            int i = cb * 512 + t;
            if (i < N_NODES * DIM / 4) {
                float4 v = ((const float4*)feat)[i];
                ((uint2*)featb_u)[i] = make_uint2(
                    f2bf(v.x) | (f2bf(v.y) << 16),
                    f2bf(v.z) | (f2bf(v.w) << 16));
            }
        } else {                        // W -> bf16 row-major (one block)
            for (int idx = t; idx < DIM * DIM; idx += 512)
                wbf[idx] = (ushort)f2bf(W[idx]);
        }
        return;
    }

    // ---- phase A: histogram ----
    for (int i = t; i < N_BUCKETS; i += 512) cnt[i] = 0;
    __syncthreads();
    const int base = bx * EPB;
    for (int k = t; k < EPB; k += 512)
        atomicAdd(&cnt[rows[base + k] >> 6], 1);
    __syncthreads();

    // ---- phase B: global reservation + LDS exclusive scan (64x13) ----
    for (int i = t; i < N_BUCKETS; i += 512) {
        int c = cnt[i];
        gbase[i] = c ? atomicAdd(&gcnt[i * GPAD], c) : 0;
    }
    if (t < 64) {
        int s = 0;
        for (int j = 0; j < 13; ++j) {
            int idx = t * 13 + j;
            if (idx < N_BUCKETS) s += cnt[idx];
        }
        csum[t] = s;
    }
    __syncthreads();
    if (t == 0) {
        int s = 0;
        for (int i = 0; i < 64; ++i) { int c = csum[i]; csum[i] = s; s += c; }
    }
    __syncthreads();
    if (t < 64) {
        int run = csum[t];
        for (int j = 0; j < 13; ++j) {
            int idx = t * 13 + j;
            if (idx < N_BUCKETS) { lcur[idx] = run; run += cnt[idx]; }
        }
    }
    __syncthreads();

    // ---- phase C: stage entries grouped by bucket ----
    for (int k = t; k < EPB; k += 512) {
        int e = base + k;
        int r = rows[e];
        int b = r >> 6;
        int pos = atomicAdd(&lcur[b], 1);
        stageE[pos] = make_int2(
            (uint)cols[e] | ((uint)(r & 63) << 16) | ((uint)b << 22),
            __float_as_int(vals[e]));
    }
    __syncthreads();

    // ---- phase D: clustered flush (slot order == destination order) ----
    for (int j = t; j < EPB; j += 512) {
        int2 p = stageE[j];
        uint b = ((uint)p.x) >> 22;
        int lb = lcur[b] - cnt[b];
        int pos = gbase[b] + (j - lb);
        if (pos < BUCKET_CAP)           // statistically impossible; safety
            perm[(size_t)b * BUCKET_CAP + pos] = p;      // agg masks b bits
    }
}

// ---------------------------------------------------------------------------
// agg_fused (unchanged from R15 -- matched prediction): 2 blocks per bucket
// (512 thr, 32 rows each; grid 1564).
// P1: compact own 32 rows into per-row LDS lists.
// P2: 4 rows/wave, bf16 gathers (lane holds feat elems 2*lane, 2*lane+1).
// P3: rows -> LDS bf16 stride 136, packed uint at word `lane` (true order).
// P4: 128x128 linear via MFMA 16x16x32 bf16 (8 waves x 2 M-tiles x 4 K-steps).
// P5: C+bias -> LDS, ReLU + LN + scale/offset -> out.
// ---------------------------------------------------------------------------
__global__ __launch_bounds__(512, 6) void agg_fused(
    const int2* __restrict__ perm, const int* __restrict__ gcnt,
    const ushort* __restrict__ featb, const ushort* __restrict__ wbf,
    const float* __restrict__ bias, const float* __restrict__ scale,
    const float* __restrict__ offset, float* __restrict__ out)
{
    __shared__ int2 lists[32 * CAPR];    // 19456 B union:
    ushort* rowsbuf = (ushort*)lists;    //   P3/P4: 32 x 136 bf16 (8704 B)
    float*  Cbuf    = (float*)lists;     //   P5:    32 x 132 fp32 (16896 B)
    __shared__ int  lcnt[32];

    const int t = threadIdx.x;
    const int b  = blockIdx.x >> 1;
    const int lo = (blockIdx.x & 1) * 32;
    if (t < 32) lcnt[t] = 0;
    __syncthreads();

    int n = gcnt[b * GPAD];
    if (n > BUCKET_CAP) n = BUCKET_CAP;
    const int2* pb = perm + (size_t)b * BUCKET_CAP;

    // ---- P1: compaction ----
    for (int e = t; e < n; e += 512) {
        int2 p = pb[e];
        int rl = ((p.x >> 16) & 63) - lo;
        if ((uint)rl < 32u) {
            int pos = atomicAdd(&lcnt[rl], 1);
            if (pos < CAPR)
                lists[rl * CAPR + pos] = make_int2(p.x & 0xFFFF, p.y);
        }
    }
    __syncthreads();

    const int lane = t & 63;
    const int wid  = t >> 6;        // 0..7
    const int rb   = wid * 4;       // this wave's first local row

    // ---- P2: gather + accumulate (ax = elem 2*lane, ay = elem 2*lane+1) ----
    float ax[4], ay[4];
    #pragma unroll
    for (int j = 0; j < 4; ++j) {
        int rl = rb + j;
        int cnt = lcnt[rl];
        if (cnt > CAPR) cnt = CAPR;
        const int2* L = &lists[rl * CAPR];
        float sx = 0.f, sy = 0.f;
        int e = 0;
        for (; e + 7 < cnt; e += 8) {
            int2 p[8]; uint g[8];
            #pragma unroll
            for (int k = 0; k < 8; ++k) p[k] = L[e + k];
            #pragma unroll
            for (int k = 0; k < 8; ++k)
                g[k] = ((const uint*)(featb + (size_t)p[k].x * DIM))[lane];
            #pragma unroll
            for (int k = 0; k < 8; ++k) {
                float v = __int_as_float(p[k].y);
                sx = fmaf(v, __uint_as_float(g[k] << 16), sx);
                sy = fmaf(v, __uint_as_float(g[k] & 0xFFFF0000u), sy);
            }
        }
        for (; e < cnt; ++e) {
            int2 p = L[e];
            uint g = ((const uint*)(featb + (size_t)p.x * DIM))[lane];
            float v = __int_as_float(p.y);
            sx = fmaf(v, __uint_as_float(g << 16), sx);
            sy = fmaf(v, __uint_as_float(g & 0xFFFF0000u), sy);
        }
        ax[j] = sx; ay[j] = sy;
    }
    __syncthreads();               // lists dead

    // ---- P3: rows -> LDS bf16 (true element order), stride 136 ushorts ----
    #pragma unroll
    for (int j = 0; j < 4; ++j) {
        uint pk = f2bf(ax[j]) | (f2bf(ay[j]) << 16);
        *(uint*)&rowsbuf[(rb + j) * 136 + 2 * lane] = pk;
    }
    __syncthreads();

    // ---- P4: MFMA GEMM.  D[m][n] = sum_k A[m][k] * W[n][k] ----
    const int l15  = lane & 15;
    const int quad = lane >> 4;
    const int n0   = wid * 16 + l15;       // this wave's N-column
    const float bb = bias[n0];

    floatx4 acc0 = {0.f, 0.f, 0.f, 0.f};   // m-tile 0 (rows 0..15)
    floatx4 acc1 = {0.f, 0.f, 0.f, 0.f};   // m-tile 1 (rows 16..31)
    #pragma unroll
    for (int kt = 0; kt < 4; ++kt) {
        int k0 = kt * 32 + quad * 8;
        short8 af0 = *(const short8*)&rowsbuf[l15 * 136 + k0];
        short8 af1 = *(const short8*)&rowsbuf[(l15 + 16) * 136 + k0];
        short8 bf  = *(const short8*)&wbf[n0 * DIM + k0];   // B[k][n]=W[n][k]
        acc0 = __builtin_amdgcn_mfma_f32_16x16x32_bf16(af0, bf, acc0, 0, 0, 0);
        acc1 = __builtin_amdgcn_mfma_f32_16x16x32_bf16(af1, bf, acc1, 0, 0, 0);
    }
    __syncthreads();               // rowsbuf dead

    // C/D layout: lane holds D[m=quad*4+r][n=l15] -> stage to Cbuf (+bias)
    #pragma unroll
    for (int r = 0; r < 4; ++r) {
        int m = quad * 4 + r;
        Cbuf[m * 132 + n0]        = acc0[r] + bb;
        Cbuf[(m + 16) * 132 + n0] = acc1[r] + bb;
    }
    __syncthreads();

    // ---- P5: ReLU + LN + scale/offset -> out (4 rows per wave) ----
    const float sc0 = scale[lane],  sc1 = scale[lane + 64];
    const float of0 = offset[lane], of1 = offset[lane + 64];

    #pragma unroll
    for (int j = 0; j < 4; ++j) {
        int rl = rb + j;
        int r  = b * ROWS_PER_BUCKET + lo + rl;
        if (r >= N_NODES) continue;                       // wave-uniform
        float A0 = fmaxf(Cbuf[rl * 132 + lane],      0.0f);
        float A1 = fmaxf(Cbuf[rl * 132 + lane + 64], 0.0f);

        float s = A0 + A1;
        #pragma unroll
        for (int off = 32; off >= 1; off >>= 1) s += __shfl_xor(s, off, 64);
        float mean = s * (1.0f / 128.0f);

        float d0 = A0 - mean, d1 = A1 - mean;
        float q = d0 * d0 + d1 * d1;
        #pragma unroll
        for (int off = 32; off >= 1; off >>= 1) q += __shfl_xor(q, off, 64);
        float rstd = rsqrtf(q * (1.0f / 128.0f) + LN_EPS);

        size_t rowp = (size_t)r * DIM;
        out[rowp + lane]      = d0 * sc0 * rstd + of0;
        out[rowp + lane + 64] = d1 * sc1 * rstd + of1;
    }
}

extern "C" void kernel_launch(void* const* d_in, const int* in_sizes, int n_in,
                              void* d_out, int out_size, void* d_ws, size_t ws_size,
                              hipStream_t stream) {
    const float* feat_in = (const float*)d_in[0];
    const int*   rows    = (const int*)d_in[1];
    const int*   cols    = (const int*)d_in[2];
    const float* vals    = (const float*)d_in[3];
    const float* W       = (const float*)d_in[4];
    const float* bias    = (const float*)d_in[5];
    const float* scale   = (const float*)d_in[6];
    const float* offset  = (const float*)d_in[7];
    float* out = (float*)d_out;

    // ---- workspace layout ----
    char* p = (char*)d_ws;
    int2* perm = (int2*)p;                 p += (size_t)N_BUCKETS * BUCKET_CAP * 8; // 16.0 MB
    ushort* featb = (ushort*)p;            p += (size_t)N_NODES * DIM * 2;          // 12.8 MB
    ushort* wbf = (ushort*)p;              p += DIM * DIM * 2;                      // 32 KB
    int*  gcnt = (int*)p;                  p += (size_t)N_BUCKETS * GPAD * 4;       // 50 KB padded

    hipMemsetAsync(gcnt, 0, (size_t)N_BUCKETS * GPAD * sizeof(int), stream);

    prep<<<SB + FCB + 1, 512, 0, stream>>>(feat_in, W, rows, cols, vals,
                                           gcnt, perm, (uint*)featb, wbf);
    agg_fused<<<N_BUCKETS * 2, 512, 0, stream>>>(perm, gcnt, featb, wbf,
                                                 bias, scale, offset, out);
}

// Round 17
// 181.824 us; speedup vs baseline: 1.0817x; 1.0817x over previous
//
#include <hip/hip_runtime.h>

typedef unsigned int uint;
typedef unsigned short ushort;
typedef __attribute__((ext_vector_type(8))) short short8;   // 8 bf16 = 4 VGPRs
typedef __attribute__((ext_vector_type(4))) float floatx4;  // MFMA C/D

#define N_NODES 50000
#define N_EDGES 1600000
#define DIM 128
#define LN_EPS 1e-10f

#define ROWS_PER_BUCKET 64
#define N_BUCKETS 782            // ceil(50000/64)
#define BUCKET_CAP 2560          // mean 2048, +11 sigma
#define EPB 6250                 // edges per scatter block (256*6250 = 1.6M exact)
#define SB 256                   // scatter blocks: one per CU
#define FCB 1563                 // feat-convert blocks (1024 thr, 1 float4 each)
#define GPAD 16                  // gcnt stride in ints (64 B/counter)
#define CAPR 76                  // per-row agg list slots (mean 32, +11 sigma)

__device__ __forceinline__ uint f2bf(float x) {
    uint u = __float_as_uint(x);
    return (u + 0x7FFFu + ((u >> 16) & 1u)) >> 16;   // RNE to bf16
}

// ---------------------------------------------------------------------------
// prep = scatter [0,SB) + feat convert + W pack, fused (R15 structure; R16's
// 512-block variant REGRESSED: scatter fixed cost scales with SB*N_BUCKETS
// and flush runs shorten).  SB=256 fills every CU with one scatter block
// (R15's 196 left 60 CUs underused) while cutting the per-block critical
// path to 6250 edges.  Algorithm: LDS histogram + rows stash -> padded
// global reservation + LDS scan -> stage-by-bucket -> clustered flush.
// ---------------------------------------------------------------------------
__global__ __launch_bounds__(1024) void prep(
    const float* __restrict__ feat, const float* __restrict__ W,
    const int* __restrict__ rows, const int* __restrict__ cols,
    const float* __restrict__ vals, int* __restrict__ gcnt,
    int2* __restrict__ perm, uint* __restrict__ featb_u,
    ushort* __restrict__ wbf)
{
    __shared__ int  cnt[N_BUCKETS];
    __shared__ int  gbase[N_BUCKETS];
    __shared__ int  lcur[N_BUCKETS];
    __shared__ int  csum[64];
    __shared__ int  stash[EPB];         // 25 KB rows
    __shared__ int2 stageE[EPB];        // 50 KB
    const int bx = blockIdx.x;
    const int t  = threadIdx.x;

    if (bx >= SB) {
        int cb = bx - SB;
        if (cb < FCB) {                 // feat fp32 -> packed bf16
            int i = cb * 1024 + t;
            if (i < N_NODES * DIM / 4) {
                float4 v = ((const float4*)feat)[i];
                ((uint2*)featb_u)[i] = make_uint2(
                    f2bf(v.x) | (f2bf(v.y) << 16),
                    f2bf(v.z) | (f2bf(v.w) << 16));
            }
        } else {                        // W -> bf16 row-major (one block)
            for (int idx = t; idx < DIM * DIM; idx += 1024)
                wbf[idx] = (ushort)f2bf(W[idx]);
        }
        return;
    }

    // ---- phase A: load rows once (stash) + histogram ----
    for (int i = t; i < N_BUCKETS; i += 1024) cnt[i] = 0;
    __syncthreads();
    const int base = bx * EPB;
    for (int k = t; k < EPB; k += 1024) {
        int r = rows[base + k];
        stash[k] = r;
        atomicAdd(&cnt[r >> 6], 1);
    }
    __syncthreads();

    // ---- phase B: global reservation + LDS exclusive scan (64x13) ----
    for (int i = t; i < N_BUCKETS; i += 1024) {
        int c = cnt[i];
        gbase[i] = c ? atomicAdd(&gcnt[i * GPAD], c) : 0;
    }
    if (t < 64) {
        int s = 0;
        for (int j = 0; j < 13; ++j) {
            int idx = t * 13 + j;
            if (idx < N_BUCKETS) s += cnt[idx];
        }
        csum[t] = s;
    }
    __syncthreads();
    if (t == 0) {
        int s = 0;
        for (int i = 0; i < 64; ++i) { int c = csum[i]; csum[i] = s; s += c; }
    }
    __syncthreads();
    if (t < 64) {
        int run = csum[t];
        for (int j = 0; j < 13; ++j) {
            int idx = t * 13 + j;
            if (idx < N_BUCKETS) { lcur[idx] = run; run += cnt[idx]; }
        }
    }
    __syncthreads();

    // ---- phase C: stage entries grouped by bucket ----
    for (int k = t; k < EPB; k += 1024) {
        int e = base + k;
        int r = stash[k];
        int b = r >> 6;
        int pos = atomicAdd(&lcur[b], 1);
        stageE[pos] = make_int2(
            (uint)cols[e] | ((uint)(r & 63) << 16) | ((uint)b << 22),
            __float_as_int(vals[e]));
    }
    __syncthreads();

    // ---- phase D: clustered flush (slot order == destination order) ----
    for (int j = t; j < EPB; j += 1024) {
        int2 p = stageE[j];
        uint b = ((uint)p.x) >> 22;
        int lb = lcur[b] - cnt[b];
        int pos = gbase[b] + (j - lb);
        if (pos < BUCKET_CAP)           // statistically impossible; safety
            perm[(size_t)b * BUCKET_CAP + pos] = p;      // agg masks b bits
    }
}

// ---------------------------------------------------------------------------
// agg_fused (unchanged from R15 -- matched prediction there): 2 blocks per
// bucket (512 thr, 32 rows each; grid 1564).
// P1: compact own 32 rows into per-row LDS lists.
// P2: 4 rows/wave, bf16 gathers (lane holds feat elems 2*lane, 2*lane+1).
// P3: rows -> LDS bf16 stride 136, packed uint at word `lane` (true order).
// P4: 128x128 linear via MFMA 16x16x32 bf16 (8 waves x 2 M-tiles x 4 K-steps).
// P5: C+bias -> LDS, ReLU + LN + scale/offset -> out.
// ---------------------------------------------------------------------------
__global__ __launch_bounds__(512, 6) void agg_fused(
    const int2* __restrict__ perm, const int* __restrict__ gcnt,
    const ushort* __restrict__ featb, const ushort* __restrict__ wbf,
    const float* __restrict__ bias, const float* __restrict__ scale,
    const float* __restrict__ offset, float* __restrict__ out)
{
    __shared__ int2 lists[32 * CAPR];    // 19456 B union:
    ushort* rowsbuf = (ushort*)lists;    //   P3/P4: 32 x 136 bf16 (8704 B)
    float*  Cbuf    = (float*)lists;     //   P5:    32 x 132 fp32 (16896 B)
    __shared__ int  lcnt[32];

    const int t = threadIdx.x;
    const int b  = blockIdx.x >> 1;
    const int lo = (blockIdx.x & 1) * 32;
    if (t < 32) lcnt[t] = 0;
    __syncthreads();

    int n = gcnt[b * GPAD];
    if (n > BUCKET_CAP) n = BUCKET_CAP;
    const int2* pb = perm + (size_t)b * BUCKET_CAP;

    // ---- P1: compaction ----
    for (int e = t; e < n; e += 512) {
        int2 p = pb[e];
        int rl = ((p.x >> 16) & 63) - lo;
        if ((uint)rl < 32u) {
            int pos = atomicAdd(&lcnt[rl], 1);
            if (pos < CAPR)
                lists[rl * CAPR + pos] = make_int2(p.x & 0xFFFF, p.y);
        }
    }
    __syncthreads();

    const int lane = t & 63;
    const int wid  = t >> 6;        // 0..7
    const int rb   = wid * 4;       // this wave's first local row

    // ---- P2: gather + accumulate (ax = elem 2*lane, ay = elem 2*lane+1) ----
    float ax[4], ay[4];
    #pragma unroll
    for (int j = 0; j < 4; ++j) {
        int rl = rb + j;
        int cnt = lcnt[rl];
        if (cnt > CAPR) cnt = CAPR;
        const int2* L = &lists[rl * CAPR];
        float sx = 0.f, sy = 0.f;
        int e = 0;
        for (; e + 7 < cnt; e += 8) {
            int2 p[8]; uint g[8];
            #pragma unroll
            for (int k = 0; k < 8; ++k) p[k] = L[e + k];
            #pragma unroll
            for (int k = 0; k < 8; ++k)
                g[k] = ((const uint*)(featb + (size_t)p[k].x * DIM))[lane];
            #pragma unroll
            for (int k = 0; k < 8; ++k) {
                float v = __int_as_float(p[k].y);
                sx = fmaf(v, __uint_as_float(g[k] << 16), sx);
                sy = fmaf(v, __uint_as_float(g[k] & 0xFFFF0000u), sy);
            }
        }
        for (; e < cnt; ++e) {
            int2 p = L[e];
            uint g = ((const uint*)(featb + (size_t)p.x * DIM))[lane];
            float v = __int_as_float(p.y);
            sx = fmaf(v, __uint_as_float(g << 16), sx);
            sy = fmaf(v, __uint_as_float(g & 0xFFFF0000u), sy);
        }
        ax[j] = sx; ay[j] = sy;
    }
    __syncthreads();               // lists dead

    // ---- P3: rows -> LDS bf16 (true element order), stride 136 ushorts ----
    #pragma unroll
    for (int j = 0; j < 4; ++j) {
        uint pk = f2bf(ax[j]) | (f2bf(ay[j]) << 16);
        *(uint*)&rowsbuf[(rb + j) * 136 + 2 * lane] = pk;
    }
    __syncthreads();

    // ---- P4: MFMA GEMM.  D[m][n] = sum_k A[m][k] * W[n][k] ----
    const int l15  = lane & 15;
    const int quad = lane >> 4;
    const int n0   = wid * 16 + l15;       // this wave's N-column
    const float bb = bias[n0];

    floatx4 acc0 = {0.f, 0.f, 0.f, 0.f};   // m-tile 0 (rows 0..15)
    floatx4 acc1 = {0.f, 0.f, 0.f, 0.f};   // m-tile 1 (rows 16..31)
    #pragma unroll
    for (int kt = 0; kt < 4; ++kt) {
        int k0 = kt * 32 + quad * 8;
        short8 af0 = *(const short8*)&rowsbuf[l15 * 136 + k0];
        short8 af1 = *(const short8*)&rowsbuf[(l15 + 16) * 136 + k0];
        short8 bf  = *(const short8*)&wbf[n0 * DIM + k0];   // B[k][n]=W[n][k]
        acc0 = __builtin_amdgcn_mfma_f32_16x16x32_bf16(af0, bf, acc0, 0, 0, 0);
        acc1 = __builtin_amdgcn_mfma_f32_16x16x32_bf16(af1, bf, acc1, 0, 0, 0);
    }
    __syncthreads();               // rowsbuf dead

    // C/D layout: lane holds D[m=quad*4+r][n=l15] -> stage to Cbuf (+bias)
    #pragma unroll
    for (int r = 0; r < 4; ++r) {
        int m = quad * 4 + r;
        Cbuf[m * 132 + n0]        = acc0[r] + bb;
        Cbuf[(m + 16) * 132 + n0] = acc1[r] + bb;
    }
    __syncthreads();

    // ---- P5: ReLU + LN + scale/offset -> out (4 rows per wave) ----
    const float sc0 = scale[lane],  sc1 = scale[lane + 64];
    const float of0 = offset[lane], of1 = offset[lane + 64];

    #pragma unroll
    for (int j = 0; j < 4; ++j) {
        int rl = rb + j;
        int r  = b * ROWS_PER_BUCKET + lo + rl;
        if (r >= N_NODES) continue;                       // wave-uniform
        float A0 = fmaxf(Cbuf[rl * 132 + lane],      0.0f);
        float A1 = fmaxf(Cbuf[rl * 132 + lane + 64], 0.0f);

        float s = A0 + A1;
        #pragma unroll
        for (int off = 32; off >= 1; off >>= 1) s += __shfl_xor(s, off, 64);
        float mean = s * (1.0f / 128.0f);

        float d0 = A0 - mean, d1 = A1 - mean;
        float q = d0 * d0 + d1 * d1;
        #pragma unroll
        for (int off = 32; off >= 1; off >>= 1) q += __shfl_xor(q, off, 64);
        float rstd = rsqrtf(q * (1.0f / 128.0f) + LN_EPS);

        size_t rowp = (size_t)r * DIM;
        out[rowp + lane]      = d0 * sc0 * rstd + of0;
        out[rowp + lane + 64] = d1 * sc1 * rstd + of1;
    }
}

extern "C" void kernel_launch(void* const* d_in, const int* in_sizes, int n_in,
                              void* d_out, int out_size, void* d_ws, size_t ws_size,
                              hipStream_t stream) {
    const float* feat_in = (const float*)d_in[0];
    const int*   rows    = (const int*)d_in[1];
    const int*   cols    = (const int*)d_in[2];
    const float* vals    = (const float*)d_in[3];
    const float* W       = (const float*)d_in[4];
    const float* bias    = (const float*)d_in[5];
    const float* scale   = (const float*)d_in[6];
    const float* offset  = (const float*)d_in[7];
    float* out = (float*)d_out;

    // ---- workspace layout ----
    char* p = (char*)d_ws;
    int2* perm = (int2*)p;                 p += (size_t)N_BUCKETS * BUCKET_CAP * 8; // 16.0 MB
    ushort* featb = (ushort*)p;            p += (size_t)N_NODES * DIM * 2;          // 12.8 MB
    ushort* wbf = (ushort*)p;              p += DIM * DIM * 2;                      // 32 KB
    int*  gcnt = (int*)p;                  p += (size_t)N_BUCKETS * GPAD * 4;       // 50 KB padded

    hipMemsetAsync(gcnt, 0, (size_t)N_BUCKETS * GPAD * sizeof(int), stream);

    prep<<<SB + FCB + 1, 1024, 0, stream>>>(feat_in, W, rows, cols, vals,
                                            gcnt, perm, (uint*)featb, wbf);
    agg_fused<<<N_BUCKETS * 2, 512, 0, stream>>>(perm, gcnt, featb, wbf,
                                                 bias, scale, offset, out);
}

// Round 18
// 175.712 us; speedup vs baseline: 1.1193x; 1.0348x over previous
//
#include <hip/hip_runtime.h>

typedef unsigned int uint;
typedef unsigned short ushort;
typedef __attribute__((ext_vector_type(8))) short short8;   // 8 bf16 = 4 VGPRs
typedef __attribute__((ext_vector_type(4))) float floatx4;  // MFMA C/D

#define N_NODES 50000
#define N_EDGES 1600000
#define DIM 128
#define LN_EPS 1e-10f

#define ROWS_PER_BUCKET 64
#define N_BUCKETS 782            // ceil(50000/64)
#define BUCKET_CAP 2560          // mean 2048, +11 sigma
#define EPB 6250                 // edges per scatter block (256*6250 = 1.6M exact)
#define SB 256                   // scatter blocks: one per CU
#define FCB 1563                 // feat-convert blocks (1024 thr, 1 float4 each)
#define CAPR 76                  // per-row agg list slots (mean 32, +11 sigma)

__device__ __forceinline__ uint f2bf(float x) {
    uint u = __float_as_uint(x);
    return (u + 0x7FFFu + ((u >> 16) & 1u)) >> 16;   // RNE to bf16
}

// ---------------------------------------------------------------------------
// prep = scatter [0,SB) + feat convert + W pack, fused.
// R18 change: phase A's histogram atomicAdd RETURN VALUE is the edge's rank
// within its bucket -- stash (rank<<16)|row and phase C places with
// pos = lbase[b] + rank, NO second LDS atomic.  Halves the per-edge LDS-RMW
// critical path (the serialized part of scatter).
// ---------------------------------------------------------------------------
__global__ __launch_bounds__(1024) void prep(
    const float* __restrict__ feat, const float* __restrict__ W,
    const int* __restrict__ rows, const int* __restrict__ cols,
    const float* __restrict__ vals, int* __restrict__ gcnt,
    int2* __restrict__ perm, uint* __restrict__ featb_u,
    ushort* __restrict__ wbf)
{
    __shared__ int  cnt[N_BUCKETS];
    __shared__ int  gbase[N_BUCKETS];
    __shared__ int  lbase[N_BUCKETS];
    __shared__ int  csum[64];
    __shared__ uint stash[EPB];         // 25 KB: (rank<<16) | row
    __shared__ int2 stageE[EPB];        // 50 KB
    const int bx = blockIdx.x;
    const int t  = threadIdx.x;

    if (bx >= SB) {
        int cb = bx - SB;
        if (cb < FCB) {                 // feat fp32 -> packed bf16
            int i = cb * 1024 + t;
            if (i < N_NODES * DIM / 4) {
                float4 v = ((const float4*)feat)[i];
                ((uint2*)featb_u)[i] = make_uint2(
                    f2bf(v.x) | (f2bf(v.y) << 16),
                    f2bf(v.z) | (f2bf(v.w) << 16));
            }
        } else {                        // W -> bf16 row-major (one block)
            for (int idx = t; idx < DIM * DIM; idx += 1024)
                wbf[idx] = (ushort)f2bf(W[idx]);
        }
        return;
    }

    // ---- phase A: rows -> rank-within-bucket (histogram's return value) ----
    for (int i = t; i < N_BUCKETS; i += 1024) cnt[i] = 0;
    __syncthreads();
    const int base = bx * EPB;
    for (int k = t; k < EPB; k += 1024) {
        int r = rows[base + k];
        int rank = atomicAdd(&cnt[r >> 6], 1);   // rank < 6250 (13 bits)
        stash[k] = ((uint)rank << 16) | (uint)r; // r < 50000 (16 bits)
    }
    __syncthreads();

    // ---- phase B: global reservation + LDS exclusive scan (64x13) ----
    for (int i = t; i < N_BUCKETS; i += 1024) {
        int c = cnt[i];
        gbase[i] = c ? atomicAdd(&gcnt[i], c) : 0;
    }
    if (t < 64) {
        int s = 0;
        for (int j = 0; j < 13; ++j) {
            int idx = t * 13 + j;
            if (idx < N_BUCKETS) s += cnt[idx];
        }
        csum[t] = s;
    }
    __syncthreads();
    if (t == 0) {
        int s = 0;
        for (int i = 0; i < 64; ++i) { int c = csum[i]; csum[i] = s; s += c; }
    }
    __syncthreads();
    if (t < 64) {
        int run = csum[t];
        for (int j = 0; j < 13; ++j) {
            int idx = t * 13 + j;
            if (idx < N_BUCKETS) { lbase[idx] = run; run += cnt[idx]; }
        }
    }
    __syncthreads();

    // ---- phase C: stage grouped by bucket -- atomic-free placement ----
    for (int k = t; k < EPB; k += 1024) {
        int e = base + k;
        uint s = stash[k];
        int r = (int)(s & 0xFFFFu);
        int rank = (int)(s >> 16);
        int b = r >> 6;
        int pos = lbase[b] + rank;
        stageE[pos] = make_int2(
            (uint)cols[e] | ((uint)(r & 63) << 16) | ((uint)b << 22),
            __float_as_int(vals[e]));
    }
    __syncthreads();

    // ---- phase D: clustered flush (slot order == destination order) ----
    for (int j = t; j < EPB; j += 1024) {
        int2 p = stageE[j];
        uint b = ((uint)p.x) >> 22;
        int pos = gbase[b] + (j - lbase[b]);
        if (pos < BUCKET_CAP)           // statistically impossible; safety
            perm[(size_t)b * BUCKET_CAP + pos] = p;      // agg masks b bits
    }
}

// ---------------------------------------------------------------------------
// agg_fused (unchanged from R15/R17 -- stable at 66 us): 2 blocks per bucket
// (512 thr, 32 rows each; grid 1564).
// P1: compact own 32 rows into per-row LDS lists.
// P2: 4 rows/wave, bf16 gathers (lane holds feat elems 2*lane, 2*lane+1).
// P3: rows -> LDS bf16 stride 136, packed uint at word `lane` (true order).
// P4: 128x128 linear via MFMA 16x16x32 bf16 (8 waves x 2 M-tiles x 4 K-steps).
// P5: C+bias -> LDS, ReLU + LN + scale/offset -> out.
// ---------------------------------------------------------------------------
__global__ __launch_bounds__(512, 6) void agg_fused(
    const int2* __restrict__ perm, const int* __restrict__ gcnt,
    const ushort* __restrict__ featb, const ushort* __restrict__ wbf,
    const float* __restrict__ bias, const float* __restrict__ scale,
    const float* __restrict__ offset, float* __restrict__ out)
{
    __shared__ int2 lists[32 * CAPR];    // 19456 B union:
    ushort* rowsbuf = (ushort*)lists;    //   P3/P4: 32 x 136 bf16 (8704 B)
    float*  Cbuf    = (float*)lists;     //   P5:    32 x 132 fp32 (16896 B)
    __shared__ int  lcnt[32];

    const int t = threadIdx.x;
    const int b  = blockIdx.x >> 1;
    const int lo = (blockIdx.x & 1) * 32;
    if (t < 32) lcnt[t] = 0;
    __syncthreads();

    int n = gcnt[b];
    if (n > BUCKET_CAP) n = BUCKET_CAP;
    const int2* pb = perm + (size_t)b * BUCKET_CAP;

    // ---- P1: compaction ----
    for (int e = t; e < n; e += 512) {
        int2 p = pb[e];
        int rl = ((p.x >> 16) & 63) - lo;
        if ((uint)rl < 32u) {
            int pos = atomicAdd(&lcnt[rl], 1);
            if (pos < CAPR)
                lists[rl * CAPR + pos] = make_int2(p.x & 0xFFFF, p.y);
        }
    }
    __syncthreads();

    const int lane = t & 63;
    const int wid  = t >> 6;        // 0..7
    const int rb   = wid * 4;       // this wave's first local row

    // ---- P2: gather + accumulate (ax = elem 2*lane, ay = elem 2*lane+1) ----
    float ax[4], ay[4];
    #pragma unroll
    for (int j = 0; j < 4; ++j) {
        int rl = rb + j;
        int cnt = lcnt[rl];
        if (cnt > CAPR) cnt = CAPR;
        const int2* L = &lists[rl * CAPR];
        float sx = 0.f, sy = 0.f;
        int e = 0;
        for (; e + 7 < cnt; e += 8) {
            int2 p[8]; uint g[8];
            #pragma unroll
            for (int k = 0; k < 8; ++k) p[k] = L[e + k];
            #pragma unroll
            for (int k = 0; k < 8; ++k)
                g[k] = ((const uint*)(featb + (size_t)p[k].x * DIM))[lane];
            #pragma unroll
            for (int k = 0; k < 8; ++k) {
                float v = __int_as_float(p[k].y);
                sx = fmaf(v, __uint_as_float(g[k] << 16), sx);
                sy = fmaf(v, __uint_as_float(g[k] & 0xFFFF0000u), sy);
            }
        }
        for (; e < cnt; ++e) {
            int2 p = L[e];
            uint g = ((const uint*)(featb + (size_t)p.x * DIM))[lane];
            float v = __int_as_float(p.y);
            sx = fmaf(v, __uint_as_float(g << 16), sx);
            sy = fmaf(v, __uint_as_float(g & 0xFFFF0000u), sy);
        }
        ax[j] = sx; ay[j] = sy;
    }
    __syncthreads();               // lists dead

    // ---- P3: rows -> LDS bf16 (true element order), stride 136 ushorts ----
    #pragma unroll
    for (int j = 0; j < 4; ++j) {
        uint pk = f2bf(ax[j]) | (f2bf(ay[j]) << 16);
        *(uint*)&rowsbuf[(rb + j) * 136 + 2 * lane] = pk;
    }
    __syncthreads();

    // ---- P4: MFMA GEMM.  D[m][n] = sum_k A[m][k] * W[n][k] ----
    const int l15  = lane & 15;
    const int quad = lane >> 4;
    const int n0   = wid * 16 + l15;       // this wave's N-column
    const float bb = bias[n0];

    floatx4 acc0 = {0.f, 0.f, 0.f, 0.f};   // m-tile 0 (rows 0..15)
    floatx4 acc1 = {0.f, 0.f, 0.f, 0.f};   // m-tile 1 (rows 16..31)
    #pragma unroll
    for (int kt = 0; kt < 4; ++kt) {
        int k0 = kt * 32 + quad * 8;
        short8 af0 = *(const short8*)&rowsbuf[l15 * 136 + k0];
        short8 af1 = *(const short8*)&rowsbuf[(l15 + 16) * 136 + k0];
        short8 bf  = *(const short8*)&wbf[n0 * DIM + k0];   // B[k][n]=W[n][k]
        acc0 = __builtin_amdgcn_mfma_f32_16x16x32_bf16(af0, bf, acc0, 0, 0, 0);
        acc1 = __builtin_amdgcn_mfma_f32_16x16x32_bf16(af1, bf, acc1, 0, 0, 0);
    }
    __syncthreads();               // rowsbuf dead

    // C/D layout: lane holds D[m=quad*4+r][n=l15] -> stage to Cbuf (+bias)
    #pragma unroll
    for (int r = 0; r < 4; ++r) {
        int m = quad * 4 + r;
        Cbuf[m * 132 + n0]        = acc0[r] + bb;
        Cbuf[(m + 16) * 132 + n0] = acc1[r] + bb;
    }
    __syncthreads();

    // ---- P5: ReLU + LN + scale/offset -> out (4 rows per wave) ----
    const float sc0 = scale[lane],  sc1 = scale[lane + 64];
    const float of0 = offset[lane], of1 = offset[lane + 64];

    #pragma unroll
    for (int j = 0; j < 4; ++j) {
        int rl = rb + j;
        int r  = b * ROWS_PER_BUCKET + lo + rl;
        if (r >= N_NODES) continue;                       // wave-uniform
        float A0 = fmaxf(Cbuf[rl * 132 + lane],      0.0f);
        float A1 = fmaxf(Cbuf[rl * 132 + lane + 64], 0.0f);

        float s = A0 + A1;
        #pragma unroll
        for (int off = 32; off >= 1; off >>= 1) s += __shfl_xor(s, off, 64);
        float mean = s * (1.0f / 128.0f);

        float d0 = A0 - mean, d1 = A1 - mean;
        float q = d0 * d0 + d1 * d1;
        #pragma unroll
        for (int off = 32; off >= 1; off >>= 1) q += __shfl_xor(q, off, 64);
        float rstd = rsqrtf(q * (1.0f / 128.0f) + LN_EPS);

        size_t rowp = (size_t)r * DIM;
        out[rowp + lane]      = d0 * sc0 * rstd + of0;
        out[rowp + lane + 64] = d1 * sc1 * rstd + of1;
    }
}

extern "C" void kernel_launch(void* const* d_in, const int* in_sizes, int n_in,
                              void* d_out, int out_size, void* d_ws, size_t ws_size,
                              hipStream_t stream) {
    const float* feat_in = (const float*)d_in[0];
    const int*   rows    = (const int*)d_in[1];
    const int*   cols    = (const int*)d_in[2];
    const float* vals    = (const float*)d_in[3];
    const float* W       = (const float*)d_in[4];
    const float* bias    = (const float*)d_in[5];
    const float* scale   = (const float*)d_in[6];
    const float* offset  = (const float*)d_in[7];
    float* out = (float*)d_out;

    // ---- workspace layout ----
    char* p = (char*)d_ws;
    int2* perm = (int2*)p;                 p += (size_t)N_BUCKETS * BUCKET_CAP * 8; // 16.0 MB
    ushort* featb = (ushort*)p;            p += (size_t)N_NODES * DIM * 2;          // 12.8 MB
    ushort* wbf = (ushort*)p;              p += DIM * DIM * 2;                      // 32 KB
    int*  gcnt = (int*)p;                  p += (size_t)(N_BUCKETS + 64) * 4;       // 3.4 KB

    hipMemsetAsync(gcnt, 0, (size_t)N_BUCKETS * sizeof(int), stream);

    prep<<<SB + FCB + 1, 1024, 0, stream>>>(feat_in, W, rows, cols, vals,
                                            gcnt, perm, (uint*)featb, wbf);
    agg_fused<<<N_BUCKETS * 2, 512, 0, stream>>>(perm, gcnt, featb, wbf,
                                                 bias, scale, offset, out);
}